// Round 11
// baseline (741.860 us; speedup 1.0000x reference)
//
#include <hip/hip_runtime.h>
#include <hip/hip_bf16.h>
#include <math.h>

// Problem constants
#define BB 2
#define SQ 2048
#define NH 8
#define DKH 64
#define DVH 192
#define CIN 1536    // NH*DVH
#define KPD 512     // NH*DKH

typedef unsigned short u16t;
typedef short bf16x8 __attribute__((ext_vector_type(8)));
typedef float f32x4 __attribute__((ext_vector_type(4)));
typedef __attribute__((address_space(3))) unsigned char lds_u8;
typedef const __attribute__((address_space(1))) unsigned char glb_u8;

__device__ __forceinline__ u16t f2bf(float f) {
    unsigned int x = __float_as_uint(f);
    unsigned int r = x + 0x7FFF + ((x >> 16) & 1);   // RNE
    return (u16t)(r >> 16);
}
__device__ __forceinline__ float bf2f(u16t u) {
    return __uint_as_float(((unsigned int)u) << 16);
}
__device__ __forceinline__ void gload16(const void* g, void* l) {
    __builtin_amdgcn_global_load_lds((glb_u8*)g, (lds_u8*)l, 16, 0, 0);
}

// ---------------------------------------------------------------------------
// Suffix sums of Wr
// ---------------------------------------------------------------------------
__global__ void suffix_kernel(const float* __restrict__ Wr,
                              float* __restrict__ SUF0, float* __restrict__ SUF1) {
    int o = blockIdx.x * 256 + threadIdx.x;
    if (o >= KPD) return;
    float s = 0.f;
    SUF0[96 * KPD + o] = 0.f;
    for (int j = 95; j >= 0; j--) { s += Wr[j * KPD + o]; SUF0[j * KPD + o] = s; }
    s = 0.f;
    SUF1[96 * KPD + o] = 0.f;
    for (int j = 95; j >= 0; j--) { s += Wr[(96 + j) * KPD + o]; SUF1[j * KPD + o] = s; }
}

// jmt[dist] = #{j : cw[j] <= dist}
__global__ void jmt_kernel(unsigned char* __restrict__ jmt) {
    int tid = threadIdx.x;
    __shared__ float cwv[96];
    double pr_d = exp(log((double)(SQ + 1)) / 96.0);
    if (tid < 96) cwv[tid] = (float)(pow(pr_d, (double)(tid + 1)) - 1.0);
    __syncthreads();
    for (int dist = tid; dist < SQ; dist += 256) {
        float ad = (float)dist;
        int jm = 0;
        for (int j = 0; j < 96; j++) jm += (cwv[j] <= ad) ? 1 : 0;
        jmt[dist] = (unsigned char)jm;
    }
}

// ---------------------------------------------------------------------------
// x -> bf16 hi/lo (elementwise)
// ---------------------------------------------------------------------------
__global__ void conv_x(const float* __restrict__ x, u16t* __restrict__ xhi,
                       u16t* __restrict__ xlo) {
    size_t i = ((size_t)blockIdx.x * 256 + threadIdx.x) * 8;
    float4 a = *(const float4*)(x + i), b4 = *(const float4*)(x + i + 4);
    float v[8] = {a.x, a.y, a.z, a.w, b4.x, b4.y, b4.z, b4.w};
    u16t hi[8], lo[8];
#pragma unroll
    for (int j = 0; j < 8; j++) {
        hi[j] = f2bf(v[j]);
        lo[j] = f2bf(v[j] - bf2f(hi[j]));
    }
    ushort4 h0 = {hi[0], hi[1], hi[2], hi[3]}, h1 = {hi[4], hi[5], hi[6], hi[7]};
    ushort4 l0 = {lo[0], lo[1], lo[2], lo[3]}, l1 = {lo[4], lo[5], lo[6], lo[7]};
    *(ushort4*)&xhi[i] = h0; *(ushort4*)&xhi[i + 4] = h1;
    *(ushort4*)&xlo[i] = l0; *(ushort4*)&xlo[i + 4] = l1;
}

// ---------------------------------------------------------------------------
// Weight transpose + bf16 hi/lo convert: src[K=1536][N] -> dst[N][1536]
// ---------------------------------------------------------------------------
__global__ __launch_bounds__(256) void tconv(
    const float* __restrict__ src, u16t* __restrict__ dhi, u16t* __restrict__ dlo, int N) {
    __shared__ float tile[64][65];
    const int k0 = blockIdx.y * 64, n0 = blockIdx.x * 64;
    const int t = threadIdx.x;
    const int lr = t >> 4, lc4 = (t & 15) * 4;
#pragma unroll
    for (int rep = 0; rep < 4; rep++) {
        int row = rep * 16 + lr;
        *(float4*)&tile[row][lc4] = *(const float4*)(src + (size_t)(k0 + row) * N + n0 + lc4);
    }
    __syncthreads();
    const int nl = t >> 2, ks = t & 3;
    u16t hi[16], lo[16];
#pragma unroll
    for (int j = 0; j < 16; j++) {
        float v = tile[ks * 16 + j][nl];
        hi[j] = f2bf(v); lo[j] = f2bf(v - bf2f(hi[j]));
    }
    size_t off = (size_t)(n0 + nl) * CIN + k0 + ks * 16;
#pragma unroll
    for (int j = 0; j < 4; j++) {
        ushort4 h = {hi[4 * j], hi[4 * j + 1], hi[4 * j + 2], hi[4 * j + 3]};
        ushort4 lo4 = {lo[4 * j], lo[4 * j + 1], lo[4 * j + 2], lo[4 * j + 3]};
        *(ushort4*)&dhi[off + 4 * j] = h;
        *(ushort4*)&dlo[off + 4 * j] = lo4;
    }
}

// ---------------------------------------------------------------------------
// A01[b,h,q][j]: j=0 -> pack(A0, A0); j>=1 -> pack(A0+A1, A0-A1)
// (hi half selected when k-q >= 0, lo half when k-q < 0)
// ---------------------------------------------------------------------------
__global__ __launch_bounds__(256) void a01_kernel(
    const float* __restrict__ Q, const float* __restrict__ SUF0,
    const float* __restrict__ SUF1, const float* __restrict__ rrb,
    unsigned int* __restrict__ A01) {
    __shared__ float s0[97][65];
    __shared__ float s1[97][65];
    __shared__ float qs[32][65];
    int h = blockIdx.y, b = blockIdx.z, qb = blockIdx.x * 32;
    int tid = threadIdx.x;
    for (int idx = tid; idx < 97 * 64; idx += 256) {
        int j = idx >> 6, e = idx & 63;
        s0[j][e] = SUF0[j * KPD + h * 64 + e];
        s1[j][e] = SUF1[j * KPD + h * 64 + e];
    }
    for (int idx = tid; idx < 32 * 64; idx += 256) {
        int q = idx >> 6, e = idx & 63;
        qs[q][e] = Q[((size_t)(b * SQ + qb + q)) * KPD + h * 64 + e] + rrb[h * 64 + e];
    }
    __syncthreads();
    int q = tid >> 3, part = tid & 7;
    for (int j = part; j < 97; j += 8) {
        float d0 = 0.f, d1 = 0.f;
        for (int e = 0; e < 64; e++) {
            float qv = qs[q][e];
            d0 += qv * s0[j][e];
            d1 += qv * s1[j][e];
        }
        float pos = (j == 0) ? d0 : (d0 + d1);
        float neg = (j == 0) ? d0 : (d0 - d1);
        unsigned int pk = ((unsigned int)f2bf(pos) << 16) | (unsigned int)f2bf(neg);
        A01[(((size_t)(b * NH + h)) * SQ + qb + q) * 97 + j] = pk;
    }
}

// ---------------------------------------------------------------------------
// 3-term hi/lo MFMA GEMM core (unchanged, known-good).
// ---------------------------------------------------------------------------
__device__ __forceinline__ void gemm3_core(
    const u16t* __restrict__ Ahi, const u16t* __restrict__ Alo,
    const u16t* __restrict__ Bhi, const u16t* __restrict__ Blo,
    u16t* lds, f32x4 (&acc)[4][4]) {
    const int tid = threadIdx.x;
    const int w = tid >> 6, l = tid & 63;
    const int lan15 = l & 15, grp = l >> 4;
    const int wr = w >> 1, wc = w & 1;

#pragma unroll
    for (int a = 0; a < 4; a++)
#pragma unroll
        for (int bq = 0; bq < 4; bq++) acc[a][bq] = (f32x4){0.f, 0.f, 0.f, 0.f};

    const u16t* gsrc = (w == 0) ? Ahi : (w == 1) ? Alo : (w == 2) ? Bhi : Blo;
    const int srow = l >> 2, sc = (l & 3) * 8;
    u16t* lbase = lds + w * 4096;

    for (int kt = 0; kt < 48; kt++) {
        const int k0 = kt * 32;
#pragma unroll
        for (int j = 0; j < 8; j++) {
            int row = j * 16 + srow;
            gload16(gsrc + (size_t)row * CIN + k0 + sc, lbase + j * 512);
        }
        __syncthreads();
        bf16x8 ah[4], al[4], bh[4], bl[4];
#pragma unroll
        for (int mi = 0; mi < 4; mi++) {
            int row = wr * 64 + mi * 16 + lan15;
            ah[mi] = *(const bf16x8*)&lds[row * 32 + grp * 8];
            al[mi] = *(const bf16x8*)&lds[4096 + row * 32 + grp * 8];
        }
#pragma unroll
        for (int ni = 0; ni < 4; ni++) {
            int row = wc * 64 + ni * 16 + lan15;
            bh[ni] = *(const bf16x8*)&lds[8192 + row * 32 + grp * 8];
            bl[ni] = *(const bf16x8*)&lds[12288 + row * 32 + grp * 8];
        }
#pragma unroll
        for (int mi = 0; mi < 4; mi++)
#pragma unroll
            for (int ni = 0; ni < 4; ni++) {
                acc[mi][ni] = __builtin_amdgcn_mfma_f32_16x16x32_bf16(ah[mi], bh[ni], acc[mi][ni], 0, 0, 0);
                acc[mi][ni] = __builtin_amdgcn_mfma_f32_16x16x32_bf16(ah[mi], bl[ni], acc[mi][ni], 0, 0, 0);
                acc[mi][ni] = __builtin_amdgcn_mfma_f32_16x16x32_bf16(al[mi], bh[ni], acc[mi][ni], 0, 0, 0);
            }
        __syncthreads();
    }
}

// Fused QKV projection (MFMA). grid (20, 32): n-space = Q(512)|K(512)|V(1536).
__global__ __launch_bounds__(256) void qkv_gemm3(
    const u16t* __restrict__ XAhi, const u16t* __restrict__ XAlo,
    const u16t* __restrict__ Whi, const u16t* __restrict__ Wlo,
    float* __restrict__ Q, u16t* __restrict__ Kbf, u16t* __restrict__ VT) {
    __shared__ __align__(16) u16t lds[16384];
    const int n0 = blockIdx.x * 128, m0 = blockIdx.y * 128;
    f32x4 acc[4][4];
    gemm3_core(XAhi + (size_t)m0 * CIN, XAlo + (size_t)m0 * CIN,
               Whi + (size_t)n0 * CIN, Wlo + (size_t)n0 * CIN, lds, acc);
    const int tid = threadIdx.x, w = tid >> 6, l = tid & 63;
    const int lan15 = l & 15, grp = l >> 4, wr = w >> 1, wc = w & 1;
    if (n0 < 512) {
#pragma unroll
        for (int mi = 0; mi < 4; mi++)
#pragma unroll
            for (int ni = 0; ni < 4; ni++) {
                int gn = n0 + wc * 64 + ni * 16 + lan15;
                int gm0 = m0 + wr * 64 + mi * 16 + grp * 4;
#pragma unroll
                for (int i = 0; i < 4; i++)
                    Q[(size_t)(gm0 + i) * KPD + gn] = acc[mi][ni][i] * 0.125f;
            }
    } else if (n0 < 1024) {
#pragma unroll
        for (int mi = 0; mi < 4; mi++)
#pragma unroll
            for (int ni = 0; ni < 4; ni++) {
                int gn = n0 - 512 + wc * 64 + ni * 16 + lan15;
                int gm0 = m0 + wr * 64 + mi * 16 + grp * 4;
#pragma unroll
                for (int i = 0; i < 4; i++)
                    Kbf[(size_t)(gm0 + i) * KPD + gn] = f2bf(acc[mi][ni][i]);
            }
    } else {
#pragma unroll
        for (int mi = 0; mi < 4; mi++)
#pragma unroll
            for (int ni = 0; ni < 4; ni++) {
                int cv = n0 - 1024 + wc * 64 + ni * 16 + lan15;
                int hh = cv / 192, dv = cv - hh * 192;
                int gm0 = m0 + wr * 64 + mi * 16 + grp * 4;
                int bidx = gm0 >> 11, s = gm0 & 2047;
                ushort4 pk = {f2bf(acc[mi][ni][0]), f2bf(acc[mi][ni][1]),
                              f2bf(acc[mi][ni][2]), f2bf(acc[mi][ni][3])};
                *(ushort4*)&VT[((size_t)(bidx * NH + hh) * 192 + dv) * SQ + s] = pk;
            }
    }
}

// Output projection (MFMA): out = ATT @ We + be. grid (12, 32).
__global__ __launch_bounds__(256) void out_gemm3(
    const u16t* __restrict__ Ahi, const u16t* __restrict__ Alo,
    const u16t* __restrict__ Whi, const u16t* __restrict__ Wlo,
    const float* __restrict__ be, float* __restrict__ out) {
    __shared__ __align__(16) u16t lds[16384];
    const int n0 = blockIdx.x * 128, m0 = blockIdx.y * 128;
    f32x4 acc[4][4];
    gemm3_core(Ahi + (size_t)m0 * CIN, Alo + (size_t)m0 * CIN,
               Whi + (size_t)n0 * CIN, Wlo + (size_t)n0 * CIN, lds, acc);
    const int tid = threadIdx.x, w = tid >> 6, l = tid & 63;
    const int lan15 = l & 15, grp = l >> 4, wr = w >> 1, wc = w & 1;
#pragma unroll
    for (int mi = 0; mi < 4; mi++)
#pragma unroll
        for (int ni = 0; ni < 4; ni++) {
            int gn = n0 + wc * 64 + ni * 16 + lan15;
            int gm0 = m0 + wr * 64 + mi * 16 + grp * 4;
            float bev = be[gn];
#pragma unroll
            for (int i = 0; i < 4; i++)
                out[(size_t)(gm0 + i) * CIN + gn] = acc[mi][ni][i] + bev;
        }
}

// ---------------------------------------------------------------------------
// MFMA flash attention, KVBLK=64, K/V direct from L2 (no staging).
// grid (S/64, H, B), 4 waves; wave owns 16 q-rows.
// Per-iteration barriers bound the LDS p_s write->read round-trip (R8's
// barrier-free variant diverged on graph replay; restored per m152 lesson).
// ---------------------------------------------------------------------------
__global__ __launch_bounds__(256) void attn_mfma(
    const float* __restrict__ Q, const u16t* __restrict__ Kbf, const u16t* __restrict__ VT,
    const unsigned int* __restrict__ A01, const unsigned char* __restrict__ jmtg,
    const float* __restrict__ rwb, u16t* __restrict__ ATThi, u16t* __restrict__ ATTlo) {
    __shared__ unsigned int a01_s[64 * 97];
    __shared__ unsigned char jmt_s[2048];
    __shared__ __align__(16) u16t p_s[4][16 * 72];   // per-wave [16 q][64 k + pad8]

    const int q0blk = blockIdx.x * 64;
    const int h = blockIdx.y, b = blockIdx.z;
    const int tid = threadIdx.x;
    const int w = tid >> 6, l = tid & 63;
    const int lan15 = l & 15, grp = l >> 4;

    // one-time stages
    ((uint2*)jmt_s)[tid] = ((const uint2*)jmtg)[tid];
    {
        const unsigned int* a01g = A01 + (((size_t)(b * NH + h)) * SQ + q0blk) * 97;
        for (int idx = tid; idx < 64 * 97; idx += 256) a01_s[idx] = a01g[idx];
    }

    // Q fragments: bf16(Q + r_w_bias)  (folds content-bias into QK^T)
    const int qrow = q0blk + w * 16 + lan15;
    bf16x8 qfrag[2];
#pragma unroll
    for (int g = 0; g < 2; g++) {
        const float* qp = Q + ((size_t)(b * SQ + qrow)) * KPD + h * 64 + g * 32 + grp * 8;
        const float* wp = rwb + h * 64 + g * 32 + grp * 8;
        float4 qa = *(const float4*)qp, qb4 = *(const float4*)(qp + 4);
        float4 wa = *(const float4*)wp, wb4 = *(const float4*)(wp + 4);
        bf16x8 f;
        f[0] = (short)f2bf(qa.x + wa.x); f[1] = (short)f2bf(qa.y + wa.y);
        f[2] = (short)f2bf(qa.z + wa.z); f[3] = (short)f2bf(qa.w + wa.w);
        f[4] = (short)f2bf(qb4.x + wb4.x); f[5] = (short)f2bf(qb4.y + wb4.y);
        f[6] = (short)f2bf(qb4.z + wb4.z); f[7] = (short)f2bf(qb4.w + wb4.w);
        qfrag[g] = f;
    }

    f32x4 o_acc[12];
#pragma unroll
    for (int c = 0; c < 12; c++) o_acc[c] = (f32x4){0.f, 0.f, 0.f, 0.f};
    float m_run[4] = {-INFINITY, -INFINITY, -INFINITY, -INFINITY};
    float l_run[4] = {0.f, 0.f, 0.f, 0.f};

    const u16t* Kbase = Kbf + ((size_t)b * SQ) * KPD + h * 64;
    const u16t* Vbase = VT + ((size_t)(b * NH + h)) * 192 * SQ;
    u16t* p_ws = p_s[w];

    __syncthreads();   // a01_s / jmt_s ready

    for (int kt = 0; kt < SQ / 64; kt++) {
        const int k0 = kt * 64;

        // ---- S = (Q+rwb) K^T : 4 col-tiles x 2 kdim-frags, K direct from L2
        f32x4 sacc[4];
#pragma unroll
        for (int ct = 0; ct < 4; ct++) {
            const u16t* kp = Kbase + (size_t)(k0 + 16 * ct + lan15) * KPD + grp * 8;
            bf16x8 kf0 = *(const bf16x8*)kp;
            bf16x8 kf1 = *(const bf16x8*)(kp + 32);
            f32x4 z = (f32x4){0.f, 0.f, 0.f, 0.f};
            z = __builtin_amdgcn_mfma_f32_16x16x32_bf16(qfrag[0], kf0, z, 0, 0, 0);
            z = __builtin_amdgcn_mfma_f32_16x16x32_bf16(qfrag[1], kf1, z, 0, 0, 0);
            sacc[ct] = z;
        }

        // ---- epilogue + online softmax (rows: q = w*16 + grp*4 + i) ----
#pragma unroll
        for (int i = 0; i < 4; i++) {
            const int qg = q0blk + w * 16 + grp * 4 + i;
            const int arow = (w * 16 + grp * 4 + i) * 97;
            float sv[4];
#pragma unroll
            for (int ct = 0; ct < 4; ct++) {
                int kg = k0 + 16 * ct + lan15;
                int dg = kg - qg;
                int dist = dg < 0 ? -dg : dg;
                unsigned int pk = a01_s[arow + (int)jmt_s[dist]];
                u16t hf = (dg >= 0) ? (u16t)(pk >> 16) : (u16t)(pk & 0xFFFF);
                sv[ct] = sacc[ct][i] + bf2f(hf);
            }
            float mx = fmaxf(fmaxf(sv[0], sv[1]), fmaxf(sv[2], sv[3]));
            mx = fmaxf(mx, __shfl_xor(mx, 1));
            mx = fmaxf(mx, __shfl_xor(mx, 2));
            mx = fmaxf(mx, __shfl_xor(mx, 4));
            mx = fmaxf(mx, __shfl_xor(mx, 8));
            float mn = fmaxf(m_run[i], mx);
            float scl = __expf(m_run[i] - mn);
            float p0 = __expf(sv[0] - mn), p1 = __expf(sv[1] - mn);
            float p2 = __expf(sv[2] - mn), p3 = __expf(sv[3] - mn);
            float ls = (p0 + p1) + (p2 + p3);
            ls += __shfl_xor(ls, 1);
            ls += __shfl_xor(ls, 2);
            ls += __shfl_xor(ls, 4);
            ls += __shfl_xor(ls, 8);
            l_run[i] = l_run[i] * scl + ls;
            m_run[i] = mn;
#pragma unroll
            for (int c = 0; c < 12; c++) o_acc[c][i] *= scl;
            const int prow = (grp * 4 + i) * 72;
            p_ws[prow + lan15]      = f2bf(p0);
            p_ws[prow + 16 + lan15] = f2bf(p1);
            p_ws[prow + 32 + lan15] = f2bf(p2);
            p_ws[prow + 48 + lan15] = f2bf(p3);
        }

        __syncthreads();   // p_s writes complete before cross-lane reads

        // ---- PV: O += P V, V direct from L2 ----
        bf16x8 pa0 = *(bf16x8*)&p_ws[lan15 * 72 + grp * 8];
        bf16x8 pa1 = *(bf16x8*)&p_ws[lan15 * 72 + 32 + grp * 8];
#pragma unroll
        for (int c = 0; c < 12; c++) {
            const u16t* vp = Vbase + (size_t)(16 * c + lan15) * SQ + k0 + grp * 8;
            bf16x8 vf0 = *(const bf16x8*)vp;
            bf16x8 vf1 = *(const bf16x8*)(vp + 32);
            o_acc[c] = __builtin_amdgcn_mfma_f32_16x16x32_bf16(pa0, vf0, o_acc[c], 0, 0, 0);
            o_acc[c] = __builtin_amdgcn_mfma_f32_16x16x32_bf16(pa1, vf1, o_acc[c], 0, 0, 0);
        }

        __syncthreads();   // reads done before next iteration overwrites p_s
    }

    // ---- write ATT (bf16 hi/lo) ----
    float inv[4];
#pragma unroll
    for (int i = 0; i < 4; i++) inv[i] = 1.f / l_run[i];
#pragma unroll
    for (int c = 0; c < 12; c++)
#pragma unroll
        for (int i = 0; i < 4; i++) {
            int qg = q0blk + w * 16 + grp * 4 + i;
            size_t idx = ((size_t)(b * SQ + qg)) * CIN + h * 192 + 16 * c + lan15;
            float o = o_acc[c][i] * inv[i];
            u16t hv = f2bf(o);
            ATThi[idx] = hv;
            ATTlo[idx] = f2bf(o - bf2f(hv));
        }
}

// ---------------------------------------------------------------------------
extern "C" void kernel_launch(void* const* d_in, const int* in_sizes, int n_in,
                              void* d_out, int out_size, void* d_ws, size_t ws_size,
                              hipStream_t stream) {
    const float* x   = (const float*)d_in[0];
    const float* Wq  = (const float*)d_in[1];
    const float* Wk  = (const float*)d_in[2];
    const float* Wv  = (const float*)d_in[3];
    const float* Wr  = (const float*)d_in[4];
    const float* rwb = (const float*)d_in[5];
    const float* rrb = (const float*)d_in[6];
    const float* We  = (const float*)d_in[7];
    const float* be  = (const float*)d_in[8];
    float* out = (float*)d_out;

    float* ws = (float*)d_ws;
    // layout (f32-word offsets). Aliases:
    //  - A01 overlays WTh/WTl (dead after qkv_gemm3; a01 runs after it)
    //  - WeTh/WeTl overlay Q+Kbf (dead after attn_mfma; their tconv runs after it)
    //  - XAhi/XAlo become ATThi/ATTlo (x dead after qkv_gemm3)
    float* Q     = ws;                                  // 2,097,152 w
    u16t*  Kbf   = (u16t*)(ws + 2097152);               // 1,048,576 w
    u16t*  VT    = (u16t*)(ws + 3145728);               // 3,145,728 w
    u16t*  XAhi  = (u16t*)(ws + 6291456);               // 3,145,728 w
    u16t*  XAlo  = (u16t*)(ws + 9437184);               // 3,145,728 w
    u16t*  WTh   = (u16t*)(ws + 12582912);              // 1,966,080 w
    u16t*  WTl   = (u16t*)(ws + 14548992);              // 1,966,080 w
    float* SUF0  = ws + 16515072;                       // 49,664 w
    float* SUF1  = ws + 16564736;                       // 49,664 w
    unsigned char* jmt = (unsigned char*)(ws + 16614400);  // 2048 B
    unsigned int* A01  = (unsigned int*)(ws + 12582912);   // 3,178,496 u32 (fits WT's 3,932,160 w)
    u16t*  WeTh  = (u16t*)(ws);                            // 1,179,648 w
    u16t*  WeTl  = (u16t*)(ws + 1179648);                  // ends 2,359,296 w (< Q+Kbf 3,145,728)
    // total ~16.62M words = 66.5 MB (63.4 MiB)

    suffix_kernel<<<2, 256, 0, stream>>>(Wr, SUF0, SUF1);
    jmt_kernel<<<1, 256, 0, stream>>>(jmt);
    conv_x<<<3072, 256, 0, stream>>>(x, XAhi, XAlo);
    tconv<<<dim3(8, 24), 256, 0, stream>>>(Wq, WTh, WTl, KPD);
    tconv<<<dim3(8, 24), 256, 0, stream>>>(Wk, WTh + (size_t)512 * CIN, WTl + (size_t)512 * CIN, KPD);
    tconv<<<dim3(24, 24), 256, 0, stream>>>(Wv, WTh + (size_t)1024 * CIN, WTl + (size_t)1024 * CIN, CIN);
    qkv_gemm3<<<dim3(20, 32), 256, 0, stream>>>(XAhi, XAlo, WTh, WTl, Q, Kbf, VT);
    a01_kernel<<<dim3(64, NH, BB), 256, 0, stream>>>(Q, SUF0, SUF1, rrb, A01);
    attn_mfma<<<dim3(SQ / 64, NH, BB), 256, 0, stream>>>(Q, Kbf, VT, A01, jmt, rwb, XAhi, XAlo);
    tconv<<<dim3(24, 24), 256, 0, stream>>>(We, WeTh, WeTl, CIN);
    out_gemm3<<<dim3(12, 32), 256, 0, stream>>>(XAhi, XAlo, WeTh, WeTl, be, out);
}